// Round 14
// baseline (166.531 us; speedup 1.0000x reference)
//
#include <hip/hip_runtime.h>
#include <hip/hip_bf16.h>

typedef __hip_bfloat16 bf16_t;
using f32x4  = __attribute__((ext_vector_type(4))) float;
using bf16x8 = __attribute__((ext_vector_type(8))) short;

#define NB 4
#define NC 64
#define NC2 32
#define NH 60
#define NW 60
#define NPIX (NH*NW)         // 3600
#define HP 66                // embed padded (pad 3)
#define MP 62                // match padded (pad 1)
#define HR 20
#define RP 22                // ref padded (pad 1)
#define NL 400
#define OHW 180
#define KPAD 512

// workspace layout (bytes) — unchanged from round-1
#define OFF_XPB   2230272
#define OFF_REFP  3214336
#define OFF_YBL   3462144
#define OFF_AP    14982144
#define OFF_EB    29727744
#define OFF_XP    32087040
#define OFF_RF    40381440

// merged conv1x1+prelu + pad-ring zeroing (round-9)
__global__ __launch_bounds__(256) void k_conv(
    const float* __restrict__ x,
    const float* __restrict__ Wa,  const float* __restrict__ ba,  const float* __restrict__ aa,
    const float* __restrict__ Wm1, const float* __restrict__ bm1, const float* __restrict__ am1,
    const float* __restrict__ Wm2, const float* __restrict__ bm2, const float* __restrict__ am2,
    bf16_t* __restrict__ E_bt, bf16_t* __restrict__ xpb, float* __restrict__ refp) {
  int bid = blockIdx.x;
  int t = threadIdx.x;
  if (bid < 300) {
    __shared__ float Ws[64*64];
    __shared__ float bs[64];
    __shared__ float al;
    int b = bid / 75, pblk = bid % 75;       // 48 pixels per block
    for (int i = t; i < 64*64; i += 256) {
      int co = i >> 6, c = i & 63;
      Ws[c*64 + co] = Wa[i];
    }
    if (t < 64) bs[t] = ba[t];
    if (t == 0) al = aa[0];
    __syncthreads();
    int lane = t & 63, wid = t >> 6;
    int pix0 = pblk*48 + wid*12;             // 12 consecutive pixels per wave
    const float* xb = x + b*NC*NPIX + pix0;  // wave-uniform base
    float acc[12];
    #pragma unroll
    for (int p = 0; p < 12; ++p) acc[p] = bs[lane];
    for (int c = 0; c < 64; ++c) {
      float wv = Ws[c*64 + lane];
      const float* xc = xb + c*NPIX;
      #pragma unroll
      for (int p = 0; p < 12; ++p)
        acc[p] = fmaf(xc[p], wv, acc[p]);
    }
    #pragma unroll
    for (int p = 0; p < 12; ++p) {
      float v = acc[p];
      v = v >= 0.f ? v : al*v;
      int pix = pix0 + p;
      int ph = pix / NW, pw = pix % NW;
      E_bt[((b*HP + ph+3)*HP + (pw+3))*NC + lane] = __float2bfloat16(v);
    }
  } else if (bid < 2100) {
    int idx = (bid - 300)*256 + t;
    int pix = idx % NPIX; int tmp = idx / NPIX;
    int co = tmp % NC2; int b = tmp / NC2;
    float alpha = am1[0];
    const float* xb = x + b*NC*NPIX + pix;
    const float* wr = Wm1 + co*64;
    float acc = bm1[co];
    #pragma unroll 8
    for (int c = 0; c < 64; ++c)
      acc = fmaf(xb[c*NPIX], wr[c], acc);
    acc = acc >= 0.f ? acc : alpha*acc;
    int ph = pix / NW, pw = pix % NW;
    xpb[((b*NC2 + co)*MP + ph+1)*MP + (pw+1)] = __float2bfloat16(acc);
  } else if (bid < 2300) {
    int idx = (bid - 2100)*256 + t;
    int pos = idx % (HR*HR); int tmp = idx / (HR*HR);
    int co = tmp % NC2; int b = tmp / NC2;
    int hr = pos / HR, wr_ = pos % HR;
    float alpha = am2[0];
    const float* xb = x + b*NC*NPIX + (3*hr+1)*NW + (3*wr_+1);
    const float* wrow = Wm2 + co*64;
    float acc = bm2[co];
    #pragma unroll 8
    for (int c = 0; c < 64; ++c)
      acc = fmaf(xb[c*NPIX], wrow[c], acc);
    acc = acc >= 0.f ? acc : alpha*acc;
    refp[((b*NC2 + co)*RP + hr+1)*RP + (wr_+1)] = acc;
  } else {
    // pad-ring zeroing (replaces memset dispatch); disjoint from interiors
    unsigned short* Eu = (unsigned short*)E_bt;
    unsigned short* Xu = (unsigned short*)xpb;
    int g0 = (bid - 2300)*256 + t;
    for (int g = g0; g < 235520; g += 80*256) {
      if (g < 193536) {
        int b = g / 48384, e = g % 48384;
        int addr;
        if (e < 25344) {
          int r6 = e / 4224, off = e % 4224;
          int ph = (r6 < 3) ? r6 : 60 + r6;          // 3->63, 4->64, 5->65
          addr = (b*HP + ph)*4224 + off;
        } else {
          int e2 = e - 25344;
          int row = e2 / 384, off2 = e2 % 384;
          int pos = (off2 < 192) ? off2 : 4032 + (off2 - 192);
          addr = (b*HP + 3 + row)*4224 + pos;
        }
        Eu[addr] = 0;
      } else if (g < 224768) {
        int gg = g - 193536;
        int p = gg / 244, e = gg % 244;
        int pos;
        if (e < 62) pos = e;                          // row 0
        else if (e < 124) pos = 3782 + (e - 62);      // row 61 (61*62)
        else { int i = e - 124; pos = (1 + (i >> 1))*62 + (i & 1)*61; }
        Xu[p*3844 + pos] = 0;
      } else {
        int gg = g - 224768;
        int p = gg / 84, e = gg % 84;
        int pos;
        if (e < 22) pos = e;                          // row 0
        else if (e < 44) pos = 462 + (e - 22);        // row 21 (21*22)
        else { int i = e - 44; pos = (1 + (i >> 1))*22 + (i & 1)*21; }
        refp[p*484 + pos] = 0.f;
      }
    }
  }
}

// merged swizzles (round-1)
__global__ __launch_bounds__(256) void k_swz(
    const bf16_t* __restrict__ xpb, const float* __restrict__ refp,
    const bf16_t* __restrict__ E_bt,
    bf16_t* __restrict__ Xp, bf16_t* __restrict__ Rf, bf16_t* __restrict__ Eb) {
  __shared__ float scl[16];
  int bid = blockIdx.x;
  int t = threadIdx.x;
  if (bid < 2025) {
    int tid = bid*256 + t;             // 518,400 total
    int slot = tid & 63; int rest = tid >> 6;
    int ks = rest % 9; int rest2 = rest / 9;
    int mblk = rest2 % 225; int b = rest2 / 225;
    int m = mblk*16 + (slot & 15);
    int h = m / NW, w = m % NW;
    int k0 = ks*32 + (slot >> 4)*8;
    const bf16_t* xb = xpb + (size_t)b*NC2*MP*MP;
    union { bf16_t a[8]; bf16x8 v; } u;
    #pragma unroll
    for (int j = 0; j < 8; ++j) {
      int k = k0 + j;
      int c = k / 9, r = k % 9;
      int i = r / 3, j2 = r % 3;
      u.a[j] = xb[(c*MP + h + i)*MP + w + j2];
    }
    *(bf16x8*)(Xp + (size_t)tid*8) = u.v;
  } else if (bid < 2125) {
    int r2 = bid - 2025;               // 100 blocks
    int nblk = r2 % 25, b = r2 / 25;
    int ll = t >> 4, sub = t & 15;     // 16 l's x 16 threads
    int l = nblk*16 + ll;
    int lh = l / HR, lw = l % HR;
    const float* rb = refp + (size_t)b*NC2*RP*RP;
    float ss = 0.f;
    #pragma unroll
    for (int e0 = 0; e0 < 18; ++e0) {
      int e = sub*18 + e0;             // 288 elems per patch
      int c = e / 9, r = e % 9;
      int i = r / 3, j = r % 3;
      float v = rb[(c*RP + lh + i)*RP + lw + j];
      ss = fmaf(v, v, ss);
    }
    #pragma unroll
    for (int off = 1; off < 16; off <<= 1)
      ss += __shfl_xor(ss, off);
    if (sub == 0) scl[ll] = 10.f / fmaxf(sqrtf(ss), 1e-4f);
    __syncthreads();
    for (int sidx = t; sidx < 576; sidx += 256) {   // 9 ks x 64 slots
      int ks = sidx >> 6, slot = sidx & 63;
      int l2 = nblk*16 + (slot & 15);
      int lh2 = l2 / HR, lw2 = l2 % HR;
      float sc = scl[slot & 15];
      int k0 = ks*32 + (slot >> 4)*8;
      union { bf16_t a[8]; bf16x8 v; } u;
      #pragma unroll
      for (int j = 0; j < 8; ++j) {
        int k = k0 + j;
        int c = k / 9, r = k % 9;
        int i = r / 3, j2 = r % 3;
        u.a[j] = __float2bfloat16(rb[(c*RP + lh2 + i)*RP + lw2 + j2] * sc);
      }
      *(bf16x8*)(Rf + ((size_t)(b*25 + nblk)*576 + sidx)*8) = u.v;
    }
  } else {
    int r2 = bid - 2125;               // 2304 blocks
    int n = r2 % 576, b = r2 / 576;
    int c = n / 9, n9 = n % 9, rr = n9 / 3, s = n9 % 3;
    size_t nbase = ((size_t)(b*12 + n/48)*16);
    const unsigned short* Eu = (const unsigned short*)E_bt;
    unsigned short* Ebu = (unsigned short*)Eb;
    for (int k = t; k < KPAD; k += 256) {
      unsigned short v = 0;
      if (k < 484) {
        int u = k / 22, vv = k % 22;
        v = Eu[((size_t)((b*HP + 3*u + rr)*HP + 3*vv + s))*NC + c];
      }
      size_t idx = (((nbase + (k>>5))*3 + (n%48)/16)*64 + ((k>>3)&3)*16 + (n&15))*8 + (k&7);
      Ebu[idx] = v;
    }
  }
}

// correlation GEMM, 2-deep prefetch, LDS-staged epilogue (round-11)
__global__ __launch_bounds__(64) void k_cgemm(
    const bf16x8* __restrict__ Xp, const bf16x8* __restrict__ Rf,
    bf16_t* __restrict__ y_bl) {
  __shared__ __align__(16) bf16_t ytile[48][80];
  int L = threadIdx.x;
  int o = blockIdx.x;                  // 0..1499
  int xcd = o & 7, sl = o >> 3;
  int w = (xcd < 4 ? xcd*188 : 752 + (xcd-4)*187) + sl;   // bijective remap
  int b = w / 375; int rem = w % 375;
  int mt = rem / 5, nt = rem % 5;
  const bf16x8* pa = Xp + ((size_t)(b*225 + mt*3)*9)*64 + L;
  const bf16x8* pb = Rf + ((size_t)(b*25 + nt*5)*9)*64 + L;
  f32x4 acc[3][5];
  #pragma unroll
  for (int i = 0; i < 3; ++i)
    #pragma unroll
    for (int j = 0; j < 5; ++j)
      acc[i][j] = {0.f, 0.f, 0.f, 0.f};
  bf16x8 A[3][3], B[3][5];
  #pragma unroll
  for (int i = 0; i < 3; ++i) { A[0][i] = pa[i*576]; A[1][i] = pa[i*576 + 64]; }
  #pragma unroll
  for (int j = 0; j < 5; ++j) { B[0][j] = pb[j*576]; B[1][j] = pb[j*576 + 64]; }
  #pragma unroll
  for (int ks = 0; ks < 9; ++ks) {
    if (ks < 7) {
      #pragma unroll
      for (int i = 0; i < 3; ++i) A[(ks+2)%3][i] = pa[i*576 + (ks+2)*64];
      #pragma unroll
      for (int j = 0; j < 5; ++j) B[(ks+2)%3][j] = pb[j*576 + (ks+2)*64];
    }
    #pragma unroll
    for (int i = 0; i < 3; ++i)
      #pragma unroll
      for (int j = 0; j < 5; ++j)
        acc[i][j] = __builtin_amdgcn_mfma_f32_16x16x32_bf16(A[ks%3][i], B[ks%3][j], acc[i][j], 0, 0, 0);
  }
  int quad = L >> 4, col = L & 15;
  #pragma unroll
  for (int mf = 0; mf < 3; ++mf)
    #pragma unroll
    for (int r = 0; r < 4; ++r)
      #pragma unroll
      for (int nf = 0; nf < 5; ++nf)
        ytile[mf*16 + quad*4 + r][nf*16 + col] = __float2bfloat16(acc[mf][nf][r]);
  __syncthreads();
  bf16_t* dst0 = y_bl + ((size_t)(b*NPIX + mt*48))*NL + nt*80;
  for (int i = L; i < 480; i += 64) {       // 48 rows x 10 bf16x8 segs
    int row = i / 10, seg = i % 10;
    *(bf16x8*)(dst0 + (size_t)row*NL + seg*8) = *(const bf16x8*)&ytile[row][seg*8];
  }
}

__device__ __forceinline__ float lo_bf(unsigned int u) {
  return __uint_as_float(u << 16);
}
__device__ __forceinline__ float hi_bf(unsigned int u) {
  return __uint_as_float(u & 0xffff0000u);
}
__device__ __forceinline__ float u16_bf(unsigned short u) {
  return __uint_as_float(((unsigned int)u) << 16);
}
__device__ __forceinline__ unsigned short bf_bits(float f) {
  union { bf16_t h; unsigned short u; } c;
  c.h = __float2bfloat16(f);
  return c.u;
}

// fused softmax + A' (round-1 structure)
__global__ __launch_bounds__(512) void k_saprime(
    const unsigned int* __restrict__ y_b32, bf16_t* __restrict__ Ap) {
  __shared__ uint4 raw[2592];                 // 41472 B: 36 slots x 576 u16
  unsigned short* ysp = (unsigned short*)raw;
  int t = threadIdx.x;
  int b = blockIdx.z;
  int h0base = blockIdx.y*4, w0base = blockIdx.x*4;   // grid (15,15,NB)
  for (int i = t; i < 2592; i += 512) raw[i] = uint4{0,0,0,0};
  __syncthreads();

  int wave = t >> 6, lane = t & 63;
  bool act = lane < 50;
  for (int pos = wave; pos < 36; pos += 8) {
    int i = pos / 6, jj = pos % 6;
    int hh = h0base - 1 + i, ww = w0base - 1 + jj;
    if (!((unsigned)hh < NH && (unsigned)ww < NW)) continue;
    const uint4* src4 = (const uint4*)(y_b32 + ((size_t)(b*NPIX + hh*NW + ww))*200);
    uint4 v = act ? src4[lane] : uint4{0,0,0,0};
    float f[8];
    if (act) {
      f[0] = lo_bf(v.x); f[1] = hi_bf(v.x);
      f[2] = lo_bf(v.y); f[3] = hi_bf(v.y);
      f[4] = lo_bf(v.z); f[5] = hi_bf(v.z);
      f[6] = lo_bf(v.w); f[7] = hi_bf(v.w);
    } else {
      #pragma unroll
      for (int k = 0; k < 8; ++k) f[k] = -1e30f;
    }
    float m = -1e30f;
    #pragma unroll
    for (int k = 0; k < 8; ++k) m = fmaxf(m, f[k]);
    #pragma unroll
    for (int off = 32; off > 0; off >>= 1)
      m = fmaxf(m, __shfl_xor(m, off));
    float s = 0.f;
    #pragma unroll
    for (int k = 0; k < 8; ++k) {
      float e = __expf(f[k] - m);
      f[k] = e;
      s += e;
    }
    #pragma unroll
    for (int off = 32; off > 0; off >>= 1)
      s += __shfl_xor(s, off);
    float r = 1.f / s;
    if (act) {
      #pragma unroll
      for (int k = 0; k < 4; ++k) {
        int l2 = lane*4 + k;                 // pair index; l = 2*l2
        int lh = l2 / 10, lw = 2*l2 - 20*lh;
        union { bf16_t h[2]; unsigned int u; } pk;
        pk.h[0] = __float2bfloat16(f[2*k]   * r);
        pk.h[1] = __float2bfloat16(f[2*k+1] * r);
        *(unsigned int*)&ysp[pos*576 + (lh+2)*24 + (lw+2)] = pk.u;
      }
    }
  }
  __syncthreads();

  int row = t >> 5;                 // 0..15
  int klane = t & 31;               // handles pair (k, k+1), k = kk*64 + 2*klane
  int h0r = row >> 2, w0r = row & 3;
  int m = (h0base + h0r)*NW + (w0base + w0r);
  int pblk = m / 80, pf = (m % 80) >> 4, mrow = m & 15;
  size_t rowbase = ((size_t)(b*45 + pblk)*16);
  const unsigned short* basep = ysp + (h0r*6 + w0r)*576;
  unsigned short* Apu = (unsigned short*)Ap;
  for (int kk = 0; kk < 8; ++kk) {
    int k = kk*64 + 2*klane;        // even; v = k%22 even -> no row straddle
    float a0 = 0.f, a1 = 0.f;
    if (k < 484) {
      int u = k / 22, v = k - 22*u;
      const unsigned short* q = basep + u*24 + v;   // even short offset
      #pragma unroll
      for (int dh = 0; dh < 3; ++dh) {
        unsigned int p0 = *(const unsigned int*)(q + dh*3480);        // dw=0
        a0 += lo_bf(p0); a1 += hi_bf(p0);
        a0 += u16_bf(q[dh*3480 + 577]);                               // dw=1
        a1 += u16_bf(q[dh*3480 + 578]);
        unsigned int p2 = *(const unsigned int*)(q + dh*3480 + 1154); // dw=2
        a0 += lo_bf(p2); a1 += hi_bf(p2);
      }
    }
    unsigned int pk = ((unsigned int)bf_bits(a1) << 16) | bf_bits(a0);
    size_t idx = (((rowbase + (k>>5))*5 + pf)*64 + ((k>>3)&3)*16 + mrow)*8 + (k&7);
    *(unsigned int*)&Apu[idx] = pk;   // idx even -> 4B aligned
  }
}

// async global->LDS issue: per-lane global src (stride 16B), wave-uniform LDS
// dest; HW writes lane i at dest + i*16  [guide §5 / m97 / m104].
__device__ __forceinline__ void gload_lds16(const bf16x8* g, bf16x8* l) {
  __builtin_amdgcn_global_load_lds(
      (const __attribute__((address_space(1))) unsigned int*)g,
      (__attribute__((address_space(3))) unsigned int*)l, 16, 0, 0);
}

// out GEMM (round-14): depth-4 async pipeline via global_load_lds.
// Single-wave blocks -> no barriers -> no compiler vmcnt(0) drain; counted
// waits via inline asm (literals under full unroll). Ring slot reuse is
// race-free: lgkmcnt(0) retires the slot's ds_reads into VGPRs before the
// refill issue. Same bytes, same MFMA order -> bit-identical output.
__global__ __launch_bounds__(64) void k_tgemm(
    const bf16x8* __restrict__ Eb, const bf16x8* __restrict__ Ap,
    float* __restrict__ out) {
  __shared__ __align__(16) bf16x8 ring[4][8][64];   // 32 KB: 4 steps x (3A+5B) x 1KB
  __shared__ __align__(16) float otile[80][52];     // 16.6 KB epilogue tile
  int L = threadIdx.x;
  int o = blockIdx.x;                  // 0..2159
  int w = (o & 7)*270 + (o >> 3);      // XCD-contiguous remap (2160 % 8 == 0)
  int b = w / 540; int rem = w % 540;
  int pbi = rem / 12, rb = rem % 12;
  const bf16x8* pa = Eb + ((size_t)(b*12 + rb)*16)*3*64 + L;
  const bf16x8* pp = Ap + ((size_t)(b*45 + pbi)*16)*5*64 + L;
  f32x4 acc[3][5];
  #pragma unroll
  for (int i = 0; i < 3; ++i)
    #pragma unroll
    for (int j = 0; j < 5; ++j)
      acc[i][j] = {0.f, 0.f, 0.f, 0.f};
  // prologue: issue steps 0..3 (32 loads, 8 per step)
  #pragma unroll
  for (int d = 0; d < 4; ++d) {
    #pragma unroll
    for (int i = 0; i < 3; ++i) gload_lds16(pa + d*192 + i*64, &ring[d][i][0]);
    #pragma unroll
    for (int j = 0; j < 5; ++j) gload_lds16(pp + d*320 + j*64, &ring[d][3+j][0]);
  }
  #pragma unroll
  for (int ks = 0; ks < 16; ++ks) {
    // wait for step ks's 8 loads (leave later steps' loads in flight)
    if (ks < 13)      asm volatile("s_waitcnt vmcnt(24)" ::: "memory");
    else if (ks == 13) asm volatile("s_waitcnt vmcnt(16)" ::: "memory");
    else if (ks == 14) asm volatile("s_waitcnt vmcnt(8)"  ::: "memory");
    else               asm volatile("s_waitcnt vmcnt(0)"  ::: "memory");
    bf16x8 af[3], bf[5];
    #pragma unroll
    for (int i = 0; i < 3; ++i) af[i] = ring[ks & 3][i][L];
    #pragma unroll
    for (int j = 0; j < 5; ++j) bf[j] = ring[ks & 3][3+j][L];
    // retire the ds_reads into VGPRs before refilling this slot
    asm volatile("s_waitcnt lgkmcnt(0)" ::: "memory");
    __builtin_amdgcn_sched_barrier(0);
    if (ks + 4 < 16) {
      int d = ks + 4;
      #pragma unroll
      for (int i = 0; i < 3; ++i) gload_lds16(pa + d*192 + i*64, &ring[d & 3][i][0]);
      #pragma unroll
      for (int j = 0; j < 5; ++j) gload_lds16(pp + d*320 + j*64, &ring[d & 3][3+j][0]);
    }
    __builtin_amdgcn_sched_barrier(0);
    #pragma unroll
    for (int i = 0; i < 3; ++i)
      #pragma unroll
      for (int j = 0; j < 5; ++j)
        acc[i][j] = __builtin_amdgcn_mfma_f32_16x16x32_bf16(af[i], bf[j], acc[i][j], 0, 0, 0);
  }
  int quad = L >> 4, col = L & 15;
  const float sc = 1.f/6.f;
  #pragma unroll
  for (int pf = 0; pf < 5; ++pf)
    #pragma unroll
    for (int rf = 0; rf < 3; ++rf) {
      f32x4 v = acc[rf][pf];
      v[0] *= sc; v[1] *= sc; v[2] *= sc; v[3] *= sc;
      *(f32x4*)&otile[pf*16 + col][rf*16 + quad*4] = v;
    }
  __syncthreads();
  if (L < 60) {
    float* ob = out + b*(NC*OHW*OHW);
    int m0 = pbi*80;
    // per-lane constants (q = L fixed) — division-free epilogue (round-13)
    int f0 = 4*L;
    int mi0 = f0/3,     s0 = f0 - 3*mi0;
    int mi1 = (f0+1)/3, s1 = (f0+1) - 3*mi1;
    int mi2 = (f0+2)/3, s2 = (f0+2) - 3*mi2;
    int mi3 = (f0+3)/3, s3 = (f0+3) - 3*mi3;
    int m  = m0 + mi0;
    int h0 = m / 60, w0 = m - 60*h0;
    int lane_off = (3*h0)*180 + 3*w0 + s0;   // + rr*180 added per p
    const float* g0 = &otile[mi0][s0];
    const float* g1 = &otile[mi1][s1];
    const float* g2 = &otile[mi2][s2];
    const float* g3 = &otile[mi3][s3];
    int rb3 = rb % 3;
    int cc = (rb*48)/9;
    int rr = rb3;
    #pragma unroll
    for (int p = 0; p < 16; ++p) {
      f32x4 v;
      v[0] = g0[p*3];
      v[1] = g1[p*3];
      v[2] = g2[p*3];
      v[3] = g3[p*3];
      *(f32x4*)&ob[cc*32400 + rr*180 + lane_off] = v;
      ++rr; if (rr == 3) { rr = 0; ++cc; }
    }
  }
}

extern "C" void kernel_launch(void* const* d_in, const int* in_sizes, int n_in,
                              void* d_out, int out_size, void* d_ws, size_t ws_size,
                              hipStream_t stream) {
  (void)in_sizes; (void)n_in; (void)out_size; (void)ws_size;
  const float* x   = (const float*)d_in[0];
  const float* Wa  = (const float*)d_in[1];
  const float* ba  = (const float*)d_in[2];
  const float* aa  = (const float*)d_in[3];
  const float* Wm1 = (const float*)d_in[4];
  const float* bm1 = (const float*)d_in[5];
  const float* am1 = (const float*)d_in[6];
  const float* Wm2 = (const float*)d_in[7];
  const float* bm2 = (const float*)d_in[8];
  const float* am2 = (const float*)d_in[9];
  float* out = (float*)d_out;

  char* base = (char*)d_ws;
  bf16_t* E_bt  = (bf16_t*)base;
  bf16_t* xpb   = (bf16_t*)(base + OFF_XPB);
  float*  refp  = (float*)(base + OFF_REFP);
  bf16_t* y_bl  = (bf16_t*)(base + OFF_YBL);
  bf16_t* ApSwz = (bf16_t*)(base + OFF_AP);
  bf16_t* EbSwz = (bf16_t*)(base + OFF_EB);
  bf16_t* XpSwz = (bf16_t*)(base + OFF_XP);
  bf16_t* RfSwz = (bf16_t*)(base + OFF_RF);

  // memset dispatch removed: pad rings zeroed inside k_conv (blocks 2300+).
  k_conv<<<2380, 256, 0, stream>>>(x, Wa, ba, aa, Wm1, bm1, am1, Wm2, bm2, am2,
                                   E_bt, xpb, refp);
  k_swz<<<4429, 256, 0, stream>>>(xpb, refp, E_bt, XpSwz, RfSwz, EbSwz);
  k_cgemm<<<1500, 64, 0, stream>>>((const bf16x8*)XpSwz, (const bf16x8*)RfSwz, y_bl);
  k_saprime<<<dim3(15, 15, NB), 512, 0, stream>>>((const unsigned int*)y_bl, ApSwz);
  k_tgemm<<<2160, 64, 0, stream>>>((const bf16x8*)EbSwz, (const bf16x8*)ApSwz, out);
}

// Round 15
// 162.720 us; speedup vs baseline: 1.0234x; 1.0234x over previous
//
#include <hip/hip_runtime.h>
#include <hip/hip_bf16.h>

typedef __hip_bfloat16 bf16_t;
using f32x4  = __attribute__((ext_vector_type(4))) float;
using bf16x8 = __attribute__((ext_vector_type(8))) short;

#define NB 4
#define NC 64
#define NC2 32
#define NH 60
#define NW 60
#define NPIX (NH*NW)         // 3600
#define HP 66                // embed padded (pad 3)
#define MP 62                // match padded (pad 1)
#define HR 20
#define RP 22                // ref padded (pad 1)
#define NL 400
#define OHW 180
#define KPAD 512

// workspace layout (bytes) — unchanged from round-1
#define OFF_XPB   2230272
#define OFF_REFP  3214336
#define OFF_YBL   3462144
#define OFF_AP    14982144
#define OFF_EB    29727744
#define OFF_XP    32087040
#define OFF_RF    40381440

// merged conv1x1+prelu + pad-ring zeroing (round-9)
__global__ __launch_bounds__(256) void k_conv(
    const float* __restrict__ x,
    const float* __restrict__ Wa,  const float* __restrict__ ba,  const float* __restrict__ aa,
    const float* __restrict__ Wm1, const float* __restrict__ bm1, const float* __restrict__ am1,
    const float* __restrict__ Wm2, const float* __restrict__ bm2, const float* __restrict__ am2,
    bf16_t* __restrict__ E_bt, bf16_t* __restrict__ xpb, float* __restrict__ refp) {
  int bid = blockIdx.x;
  int t = threadIdx.x;
  if (bid < 300) {
    __shared__ float Ws[64*64];
    __shared__ float bs[64];
    __shared__ float al;
    int b = bid / 75, pblk = bid % 75;       // 48 pixels per block
    for (int i = t; i < 64*64; i += 256) {
      int co = i >> 6, c = i & 63;
      Ws[c*64 + co] = Wa[i];
    }
    if (t < 64) bs[t] = ba[t];
    if (t == 0) al = aa[0];
    __syncthreads();
    int lane = t & 63, wid = t >> 6;
    int pix0 = pblk*48 + wid*12;             // 12 consecutive pixels per wave
    const float* xb = x + b*NC*NPIX + pix0;  // wave-uniform base
    float acc[12];
    #pragma unroll
    for (int p = 0; p < 12; ++p) acc[p] = bs[lane];
    for (int c = 0; c < 64; ++c) {
      float wv = Ws[c*64 + lane];
      const float* xc = xb + c*NPIX;
      #pragma unroll
      for (int p = 0; p < 12; ++p)
        acc[p] = fmaf(xc[p], wv, acc[p]);
    }
    #pragma unroll
    for (int p = 0; p < 12; ++p) {
      float v = acc[p];
      v = v >= 0.f ? v : al*v;
      int pix = pix0 + p;
      int ph = pix / NW, pw = pix % NW;
      E_bt[((b*HP + ph+3)*HP + (pw+3))*NC + lane] = __float2bfloat16(v);
    }
  } else if (bid < 2100) {
    int idx = (bid - 300)*256 + t;
    int pix = idx % NPIX; int tmp = idx / NPIX;
    int co = tmp % NC2; int b = tmp / NC2;
    float alpha = am1[0];
    const float* xb = x + b*NC*NPIX + pix;
    const float* wr = Wm1 + co*64;
    float acc = bm1[co];
    #pragma unroll 8
    for (int c = 0; c < 64; ++c)
      acc = fmaf(xb[c*NPIX], wr[c], acc);
    acc = acc >= 0.f ? acc : alpha*acc;
    int ph = pix / NW, pw = pix % NW;
    xpb[((b*NC2 + co)*MP + ph+1)*MP + (pw+1)] = __float2bfloat16(acc);
  } else if (bid < 2300) {
    int idx = (bid - 2100)*256 + t;
    int pos = idx % (HR*HR); int tmp = idx / (HR*HR);
    int co = tmp % NC2; int b = tmp / NC2;
    int hr = pos / HR, wr_ = pos % HR;
    float alpha = am2[0];
    const float* xb = x + b*NC*NPIX + (3*hr+1)*NW + (3*wr_+1);
    const float* wrow = Wm2 + co*64;
    float acc = bm2[co];
    #pragma unroll 8
    for (int c = 0; c < 64; ++c)
      acc = fmaf(xb[c*NPIX], wrow[c], acc);
    acc = acc >= 0.f ? acc : alpha*acc;
    refp[((b*NC2 + co)*RP + hr+1)*RP + (wr_+1)] = acc;
  } else {
    // pad-ring zeroing (replaces memset dispatch); disjoint from interiors
    unsigned short* Eu = (unsigned short*)E_bt;
    unsigned short* Xu = (unsigned short*)xpb;
    int g0 = (bid - 2300)*256 + t;
    for (int g = g0; g < 235520; g += 80*256) {
      if (g < 193536) {
        int b = g / 48384, e = g % 48384;
        int addr;
        if (e < 25344) {
          int r6 = e / 4224, off = e % 4224;
          int ph = (r6 < 3) ? r6 : 60 + r6;          // 3->63, 4->64, 5->65
          addr = (b*HP + ph)*4224 + off;
        } else {
          int e2 = e - 25344;
          int row = e2 / 384, off2 = e2 % 384;
          int pos = (off2 < 192) ? off2 : 4032 + (off2 - 192);
          addr = (b*HP + 3 + row)*4224 + pos;
        }
        Eu[addr] = 0;
      } else if (g < 224768) {
        int gg = g - 193536;
        int p = gg / 244, e = gg % 244;
        int pos;
        if (e < 62) pos = e;                          // row 0
        else if (e < 124) pos = 3782 + (e - 62);      // row 61 (61*62)
        else { int i = e - 124; pos = (1 + (i >> 1))*62 + (i & 1)*61; }
        Xu[p*3844 + pos] = 0;
      } else {
        int gg = g - 224768;
        int p = gg / 84, e = gg % 84;
        int pos;
        if (e < 22) pos = e;                          // row 0
        else if (e < 44) pos = 462 + (e - 22);        // row 21 (21*22)
        else { int i = e - 44; pos = (1 + (i >> 1))*22 + (i & 1)*21; }
        refp[p*484 + pos] = 0.f;
      }
    }
  }
}

// merged swizzles (round-1)
__global__ __launch_bounds__(256) void k_swz(
    const bf16_t* __restrict__ xpb, const float* __restrict__ refp,
    const bf16_t* __restrict__ E_bt,
    bf16_t* __restrict__ Xp, bf16_t* __restrict__ Rf, bf16_t* __restrict__ Eb) {
  __shared__ float scl[16];
  int bid = blockIdx.x;
  int t = threadIdx.x;
  if (bid < 2025) {
    int tid = bid*256 + t;             // 518,400 total
    int slot = tid & 63; int rest = tid >> 6;
    int ks = rest % 9; int rest2 = rest / 9;
    int mblk = rest2 % 225; int b = rest2 / 225;
    int m = mblk*16 + (slot & 15);
    int h = m / NW, w = m % NW;
    int k0 = ks*32 + (slot >> 4)*8;
    const bf16_t* xb = xpb + (size_t)b*NC2*MP*MP;
    union { bf16_t a[8]; bf16x8 v; } u;
    #pragma unroll
    for (int j = 0; j < 8; ++j) {
      int k = k0 + j;
      int c = k / 9, r = k % 9;
      int i = r / 3, j2 = r % 3;
      u.a[j] = xb[(c*MP + h + i)*MP + w + j2];
    }
    *(bf16x8*)(Xp + (size_t)tid*8) = u.v;
  } else if (bid < 2125) {
    int r2 = bid - 2025;               // 100 blocks
    int nblk = r2 % 25, b = r2 / 25;
    int ll = t >> 4, sub = t & 15;     // 16 l's x 16 threads
    int l = nblk*16 + ll;
    int lh = l / HR, lw = l % HR;
    const float* rb = refp + (size_t)b*NC2*RP*RP;
    float ss = 0.f;
    #pragma unroll
    for (int e0 = 0; e0 < 18; ++e0) {
      int e = sub*18 + e0;             // 288 elems per patch
      int c = e / 9, r = e % 9;
      int i = r / 3, j = r % 3;
      float v = rb[(c*RP + lh + i)*RP + lw + j];
      ss = fmaf(v, v, ss);
    }
    #pragma unroll
    for (int off = 1; off < 16; off <<= 1)
      ss += __shfl_xor(ss, off);
    if (sub == 0) scl[ll] = 10.f / fmaxf(sqrtf(ss), 1e-4f);
    __syncthreads();
    for (int sidx = t; sidx < 576; sidx += 256) {   // 9 ks x 64 slots
      int ks = sidx >> 6, slot = sidx & 63;
      int l2 = nblk*16 + (slot & 15);
      int lh2 = l2 / HR, lw2 = l2 % HR;
      float sc = scl[slot & 15];
      int k0 = ks*32 + (slot >> 4)*8;
      union { bf16_t a[8]; bf16x8 v; } u;
      #pragma unroll
      for (int j = 0; j < 8; ++j) {
        int k = k0 + j;
        int c = k / 9, r = k % 9;
        int i = r / 3, j2 = r % 3;
        u.a[j] = __float2bfloat16(rb[(c*RP + lh2 + i)*RP + lw2 + j2] * sc);
      }
      *(bf16x8*)(Rf + ((size_t)(b*25 + nblk)*576 + sidx)*8) = u.v;
    }
  } else {
    int r2 = bid - 2125;               // 2304 blocks
    int n = r2 % 576, b = r2 / 576;
    int c = n / 9, n9 = n % 9, rr = n9 / 3, s = n9 % 3;
    size_t nbase = ((size_t)(b*12 + n/48)*16);
    const unsigned short* Eu = (const unsigned short*)E_bt;
    unsigned short* Ebu = (unsigned short*)Eb;
    for (int k = t; k < KPAD; k += 256) {
      unsigned short v = 0;
      if (k < 484) {
        int u = k / 22, vv = k % 22;
        v = Eu[((size_t)((b*HP + 3*u + rr)*HP + 3*vv + s))*NC + c];
      }
      size_t idx = (((nbase + (k>>5))*3 + (n%48)/16)*64 + ((k>>3)&3)*16 + (n&15))*8 + (k&7);
      Ebu[idx] = v;
    }
  }
}

// correlation GEMM, 2-deep prefetch, LDS-staged epilogue (round-11)
__global__ __launch_bounds__(64) void k_cgemm(
    const bf16x8* __restrict__ Xp, const bf16x8* __restrict__ Rf,
    bf16_t* __restrict__ y_bl) {
  __shared__ __align__(16) bf16_t ytile[48][80];
  int L = threadIdx.x;
  int o = blockIdx.x;                  // 0..1499
  int xcd = o & 7, sl = o >> 3;
  int w = (xcd < 4 ? xcd*188 : 752 + (xcd-4)*187) + sl;   // bijective remap
  int b = w / 375; int rem = w % 375;
  int mt = rem / 5, nt = rem % 5;
  const bf16x8* pa = Xp + ((size_t)(b*225 + mt*3)*9)*64 + L;
  const bf16x8* pb = Rf + ((size_t)(b*25 + nt*5)*9)*64 + L;
  f32x4 acc[3][5];
  #pragma unroll
  for (int i = 0; i < 3; ++i)
    #pragma unroll
    for (int j = 0; j < 5; ++j)
      acc[i][j] = {0.f, 0.f, 0.f, 0.f};
  bf16x8 A[3][3], B[3][5];
  #pragma unroll
  for (int i = 0; i < 3; ++i) { A[0][i] = pa[i*576]; A[1][i] = pa[i*576 + 64]; }
  #pragma unroll
  for (int j = 0; j < 5; ++j) { B[0][j] = pb[j*576]; B[1][j] = pb[j*576 + 64]; }
  #pragma unroll
  for (int ks = 0; ks < 9; ++ks) {
    if (ks < 7) {
      #pragma unroll
      for (int i = 0; i < 3; ++i) A[(ks+2)%3][i] = pa[i*576 + (ks+2)*64];
      #pragma unroll
      for (int j = 0; j < 5; ++j) B[(ks+2)%3][j] = pb[j*576 + (ks+2)*64];
    }
    #pragma unroll
    for (int i = 0; i < 3; ++i)
      #pragma unroll
      for (int j = 0; j < 5; ++j)
        acc[i][j] = __builtin_amdgcn_mfma_f32_16x16x32_bf16(A[ks%3][i], B[ks%3][j], acc[i][j], 0, 0, 0);
  }
  int quad = L >> 4, col = L & 15;
  #pragma unroll
  for (int mf = 0; mf < 3; ++mf)
    #pragma unroll
    for (int r = 0; r < 4; ++r)
      #pragma unroll
      for (int nf = 0; nf < 5; ++nf)
        ytile[mf*16 + quad*4 + r][nf*16 + col] = __float2bfloat16(acc[mf][nf][r]);
  __syncthreads();
  bf16_t* dst0 = y_bl + ((size_t)(b*NPIX + mt*48))*NL + nt*80;
  for (int i = L; i < 480; i += 64) {       // 48 rows x 10 bf16x8 segs
    int row = i / 10, seg = i % 10;
    *(bf16x8*)(dst0 + (size_t)row*NL + seg*8) = *(const bf16x8*)&ytile[row][seg*8];
  }
}

__device__ __forceinline__ float lo_bf(unsigned int u) {
  return __uint_as_float(u << 16);
}
__device__ __forceinline__ float hi_bf(unsigned int u) {
  return __uint_as_float(u & 0xffff0000u);
}
__device__ __forceinline__ float u16_bf(unsigned short u) {
  return __uint_as_float(((unsigned int)u) << 16);
}
__device__ __forceinline__ unsigned short bf_bits(float f) {
  union { bf16_t h; unsigned short u; } c;
  c.h = __float2bfloat16(f);
  return c.u;
}

// fused softmax + A' (round-1 structure)
__global__ __launch_bounds__(512) void k_saprime(
    const unsigned int* __restrict__ y_b32, bf16_t* __restrict__ Ap) {
  __shared__ uint4 raw[2592];                 // 41472 B: 36 slots x 576 u16
  unsigned short* ysp = (unsigned short*)raw;
  int t = threadIdx.x;
  int b = blockIdx.z;
  int h0base = blockIdx.y*4, w0base = blockIdx.x*4;   // grid (15,15,NB)
  for (int i = t; i < 2592; i += 512) raw[i] = uint4{0,0,0,0};
  __syncthreads();

  int wave = t >> 6, lane = t & 63;
  bool act = lane < 50;
  for (int pos = wave; pos < 36; pos += 8) {
    int i = pos / 6, jj = pos % 6;
    int hh = h0base - 1 + i, ww = w0base - 1 + jj;
    if (!((unsigned)hh < NH && (unsigned)ww < NW)) continue;
    const uint4* src4 = (const uint4*)(y_b32 + ((size_t)(b*NPIX + hh*NW + ww))*200);
    uint4 v = act ? src4[lane] : uint4{0,0,0,0};
    float f[8];
    if (act) {
      f[0] = lo_bf(v.x); f[1] = hi_bf(v.x);
      f[2] = lo_bf(v.y); f[3] = hi_bf(v.y);
      f[4] = lo_bf(v.z); f[5] = hi_bf(v.z);
      f[6] = lo_bf(v.w); f[7] = hi_bf(v.w);
    } else {
      #pragma unroll
      for (int k = 0; k < 8; ++k) f[k] = -1e30f;
    }
    float m = -1e30f;
    #pragma unroll
    for (int k = 0; k < 8; ++k) m = fmaxf(m, f[k]);
    #pragma unroll
    for (int off = 32; off > 0; off >>= 1)
      m = fmaxf(m, __shfl_xor(m, off));
    float s = 0.f;
    #pragma unroll
    for (int k = 0; k < 8; ++k) {
      float e = __expf(f[k] - m);
      f[k] = e;
      s += e;
    }
    #pragma unroll
    for (int off = 32; off > 0; off >>= 1)
      s += __shfl_xor(s, off);
    float r = 1.f / s;
    if (act) {
      #pragma unroll
      for (int k = 0; k < 4; ++k) {
        int l2 = lane*4 + k;                 // pair index; l = 2*l2
        int lh = l2 / 10, lw = 2*l2 - 20*lh;
        union { bf16_t h[2]; unsigned int u; } pk;
        pk.h[0] = __float2bfloat16(f[2*k]   * r);
        pk.h[1] = __float2bfloat16(f[2*k+1] * r);
        *(unsigned int*)&ysp[pos*576 + (lh+2)*24 + (lw+2)] = pk.u;
      }
    }
  }
  __syncthreads();

  int row = t >> 5;                 // 0..15
  int klane = t & 31;               // handles pair (k, k+1), k = kk*64 + 2*klane
  int h0r = row >> 2, w0r = row & 3;
  int m = (h0base + h0r)*NW + (w0base + w0r);
  int pblk = m / 80, pf = (m % 80) >> 4, mrow = m & 15;
  size_t rowbase = ((size_t)(b*45 + pblk)*16);
  const unsigned short* basep = ysp + (h0r*6 + w0r)*576;
  unsigned short* Apu = (unsigned short*)Ap;
  for (int kk = 0; kk < 8; ++kk) {
    int k = kk*64 + 2*klane;        // even; v = k%22 even -> no row straddle
    float a0 = 0.f, a1 = 0.f;
    if (k < 484) {
      int u = k / 22, v = k - 22*u;
      const unsigned short* q = basep + u*24 + v;   // even short offset
      #pragma unroll
      for (int dh = 0; dh < 3; ++dh) {
        unsigned int p0 = *(const unsigned int*)(q + dh*3480);        // dw=0
        a0 += lo_bf(p0); a1 += hi_bf(p0);
        a0 += u16_bf(q[dh*3480 + 577]);                               // dw=1
        a1 += u16_bf(q[dh*3480 + 578]);
        unsigned int p2 = *(const unsigned int*)(q + dh*3480 + 1154); // dw=2
        a0 += lo_bf(p2); a1 += hi_bf(p2);
      }
    }
    unsigned int pk = ((unsigned int)bf_bits(a1) << 16) | bf_bits(a0);
    size_t idx = (((rowbase + (k>>5))*5 + pf)*64 + ((k>>3)&3)*16 + mrow)*8 + (k&7);
    *(unsigned int*)&Apu[idx] = pk;   // idx even -> 4B aligned
  }
}

// out GEMM (round-13 final): 3-slot-ring K-loop + division-free epilogue.
__global__ __launch_bounds__(64) void k_tgemm(
    const bf16x8* __restrict__ Eb, const bf16x8* __restrict__ Ap,
    float* __restrict__ out) {
  __shared__ __align__(16) float otile[80][52];   // [m_local][n_local], pad 48->52
  int L = threadIdx.x;
  int o = blockIdx.x;                  // 0..2159
  int w = (o & 7)*270 + (o >> 3);      // XCD-contiguous remap (2160 % 8 == 0)
  int b = w / 540; int rem = w % 540;
  int pbi = rem / 12, rb = rem % 12;
  const bf16x8* pa = Eb + ((size_t)(b*12 + rb)*16)*3*64 + L;
  const bf16x8* pp = Ap + ((size_t)(b*45 + pbi)*16)*5*64 + L;
  f32x4 acc[3][5];
  #pragma unroll
  for (int i = 0; i < 3; ++i)
    #pragma unroll
    for (int j = 0; j < 5; ++j)
      acc[i][j] = {0.f, 0.f, 0.f, 0.f};
  bf16x8 A[3][3], B[3][5];
  #pragma unroll
  for (int i = 0; i < 3; ++i) { A[0][i] = pa[i*64]; A[1][i] = pa[192 + i*64]; }
  #pragma unroll
  for (int j = 0; j < 5; ++j) { B[0][j] = pp[j*64]; B[1][j] = pp[320 + j*64]; }
  #pragma unroll
  for (int ks = 0; ks < 16; ++ks) {
    if (ks < 14) {
      const bf16x8* na = pa + (ks+2)*192;
      const bf16x8* nb = pp + (ks+2)*320;
      #pragma unroll
      for (int i = 0; i < 3; ++i) A[(ks+2)%3][i] = na[i*64];
      #pragma unroll
      for (int j = 0; j < 5; ++j) B[(ks+2)%3][j] = nb[j*64];
    }
    #pragma unroll
    for (int i = 0; i < 3; ++i)
      #pragma unroll
      for (int j = 0; j < 5; ++j)
        acc[i][j] = __builtin_amdgcn_mfma_f32_16x16x32_bf16(A[ks%3][i], B[ks%3][j], acc[i][j], 0, 0, 0);
  }
  int quad = L >> 4, col = L & 15;
  const float sc = 1.f/6.f;
  #pragma unroll
  for (int pf = 0; pf < 5; ++pf)
    #pragma unroll
    for (int rf = 0; rf < 3; ++rf) {
      f32x4 v = acc[rf][pf];
      v[0] *= sc; v[1] *= sc; v[2] *= sc; v[3] *= sc;
      *(f32x4*)&otile[pf*16 + col][rf*16 + quad*4] = v;
    }
  __syncthreads();
  if (L < 60) {
    float* ob = out + b*(NC*OHW*OHW);
    int m0 = pbi*80;
    // per-lane constants (q = L fixed) — division-free epilogue (round-13)
    int f0 = 4*L;
    int mi0 = f0/3,     s0 = f0 - 3*mi0;
    int mi1 = (f0+1)/3, s1 = (f0+1) - 3*mi1;
    int mi2 = (f0+2)/3, s2 = (f0+2) - 3*mi2;
    int mi3 = (f0+3)/3, s3 = (f0+3) - 3*mi3;
    int m  = m0 + mi0;
    int h0 = m / 60, w0 = m - 60*h0;
    int lane_off = (3*h0)*180 + 3*w0 + s0;   // + rr*180 added per p
    const float* g0 = &otile[mi0][s0];
    const float* g1 = &otile[mi1][s1];
    const float* g2 = &otile[mi2][s2];
    const float* g3 = &otile[mi3][s3];
    int rb3 = rb % 3;
    int cc = (rb*48)/9;
    int rr = rb3;
    #pragma unroll
    for (int p = 0; p < 16; ++p) {
      f32x4 v;
      v[0] = g0[p*3];
      v[1] = g1[p*3];
      v[2] = g2[p*3];
      v[3] = g3[p*3];
      *(f32x4*)&ob[cc*32400 + rr*180 + lane_off] = v;
      ++rr; if (rr == 3) { rr = 0; ++cc; }
    }
  }
}

extern "C" void kernel_launch(void* const* d_in, const int* in_sizes, int n_in,
                              void* d_out, int out_size, void* d_ws, size_t ws_size,
                              hipStream_t stream) {
  (void)in_sizes; (void)n_in; (void)out_size; (void)ws_size;
  const float* x   = (const float*)d_in[0];
  const float* Wa  = (const float*)d_in[1];
  const float* ba  = (const float*)d_in[2];
  const float* aa  = (const float*)d_in[3];
  const float* Wm1 = (const float*)d_in[4];
  const float* bm1 = (const float*)d_in[5];
  const float* am1 = (const float*)d_in[6];
  const float* Wm2 = (const float*)d_in[7];
  const float* bm2 = (const float*)d_in[8];
  const float* am2 = (const float*)d_in[9];
  float* out = (float*)d_out;

  char* base = (char*)d_ws;
  bf16_t* E_bt  = (bf16_t*)base;
  bf16_t* xpb   = (bf16_t*)(base + OFF_XPB);
  float*  refp  = (float*)(base + OFF_REFP);
  bf16_t* y_bl  = (bf16_t*)(base + OFF_YBL);
  bf16_t* ApSwz = (bf16_t*)(base + OFF_AP);
  bf16_t* EbSwz = (bf16_t*)(base + OFF_EB);
  bf16_t* XpSwz = (bf16_t*)(base + OFF_XP);
  bf16_t* RfSwz = (bf16_t*)(base + OFF_RF);

  // memset dispatch removed: pad rings zeroed inside k_conv (blocks 2300+).
  k_conv<<<2380, 256, 0, stream>>>(x, Wa, ba, aa, Wm1, bm1, am1, Wm2, bm2, am2,
                                   E_bt, xpb, refp);
  k_swz<<<4429, 256, 0, stream>>>(xpb, refp, E_bt, XpSwz, RfSwz, EbSwz);
  k_cgemm<<<1500, 64, 0, stream>>>((const bf16x8*)XpSwz, (const bf16x8*)RfSwz, y_bl);
  k_saprime<<<dim3(15, 15, NB), 512, 0, stream>>>((const unsigned int*)y_bl, ApSwz);
  k_tgemm<<<2160, 64, 0, stream>>>((const bf16x8*)EbSwz, (const bf16x8*)ApSwz, out);
}